// Round 5
// baseline (169.352 us; speedup 1.0000x reference)
//
#include <hip/hip_runtime.h>
#include <hip/hip_bf16.h>
#include <math.h>

#define NH 16
#define HS 64
#define DE 1024
#define TT 1024
#define BBATCH 4
#define MTOK 4096   // B*T

typedef __bf16 v8bf __attribute__((ext_vector_type(8)));
typedef __bf16 v4bf __attribute__((ext_vector_type(4)));
typedef float  v4f  __attribute__((ext_vector_type(4)));

__device__ __forceinline__ void gl_lds16(const __bf16* g, __bf16* l) {
    __builtin_amdgcn_global_load_lds(
        (const __attribute__((address_space(1))) unsigned int*)g,
        (__attribute__((address_space(3))) unsigned int*)l, 16, 0, 0);
}

__device__ __forceinline__ v4f bf_mfma(v8bf a, v8bf b, v4f c) {
    return __builtin_amdgcn_mfma_f32_16x16x32_bf16(a, b, c, 0, 0, 0);
}

__device__ __forceinline__ void wg_barrier() {
    asm volatile("" ::: "memory");
    __builtin_amdgcn_s_barrier();
    asm volatile("" ::: "memory");
}

// ---------------- fused prep: cast x (1048576 f4), cast Wo (262144 f4), transpose Wq/Wk/Wv ----
__global__ __launch_bounds__(256) void prep_all_kernel(
    const float* __restrict__ x,  __bf16* __restrict__ xb,
    const float* __restrict__ Wo, __bf16* __restrict__ Wob,
    const float* __restrict__ Wq, const float* __restrict__ Wk,
    const float* __restrict__ Wv, __bf16* __restrict__ Wt)
{
    const int bid = blockIdx.x;
    const int t = threadIdx.x;
    if (bid < 5120) {
        int i = bid * 256 + t;
        const float* in; __bf16* out;
        if (i < 1048576) { in = x;  out = xb; }
        else             { in = Wo; out = Wob; i -= 1048576; }
        float4 v = ((const float4*)in)[i];
        v4bf o;
        o[0] = (__bf16)v.x; o[1] = (__bf16)v.y; o[2] = (__bf16)v.z; o[3] = (__bf16)v.w;
        *(v4bf*)&out[(size_t)i * 4] = o;
        return;
    }
    const int bid2 = bid - 5120;
    const int c0 = (bid2 & 15) * 64, h = (bid2 >> 4) & 15, m = bid2 >> 8;
    const float* W = (m == 0) ? Wq : (m == 1) ? Wk : Wv;
    __shared__ float tile[64][65];
    #pragma unroll
    for (int pp = 0; pp < 16; ++pp) {
        int cl = pp * 4 + (t >> 6);
        int s  = t & 63;
        tile[cl][s] = W[((size_t)h * DE + c0 + cl) * HS + s];
    }
    __syncthreads();
    #pragma unroll
    for (int pp = 0; pp < 16; ++pp) {
        int s  = pp * 4 + (t >> 6);
        int cl = t & 63;
        Wt[((size_t)(m * DE + h * HS + s)) * DE + c0 + cl] = (__bf16)tile[cl][s];
    }
}

// ================= QKV GEMM v3: 256x256 8-phase, reads-BEFORE-barrier (template-faithful) ====
// 512 thr = 8 waves (2M x 4N); BK=64; LDS 128KB dbuf.
// Per phase: {ds_read frag subtile from cur || stage 1 half of t+1} -> barrier ->
//            16 MFMA (setprio, compiler-emitted fine lgkmcnt) -> barrier.
// vmcnt gate once per K-tile at the boundary: t0 vmcnt(8), steady vmcnt(2), last vmcnt(0).
__device__ __forceinline__ void stage_half(
    const __bf16* __restrict__ Gb, __bf16* Ls, int h, int k0, int tid)
{
    #pragma unroll
    for (int i = 0; i < 2; ++i) {
        int p  = i * 512 + tid;
        int r  = p >> 3;                 // 0..127 within half
        int lc = (p & 7) ^ (r & 7);      // pre-swizzled global granule
        gl_lds16(Gb + (size_t)(h * 128 + r) * 1024 + k0 + lc * 8, Ls + h * 128 * 64 + p * 8);
    }
}

__global__ __launch_bounds__(512, 2) void gemm_qkv_8ph(
    const __bf16* __restrict__ A, const __bf16* __restrict__ Bt,
    __bf16* __restrict__ qk_out, __bf16* __restrict__ vt_out)
{
    __shared__ __align__(16) __bf16 As[2][256 * 64];
    __shared__ __align__(16) __bf16 Bs[2][256 * 64];
    const int tid = threadIdx.x;
    const int w = tid >> 6, l = tid & 63;
    const int wm = w >> 2, wn = w & 3;          // 2M x 4N waves
    const int lhi = l >> 4, llo = l & 15;
    const int sw0 = ((lhi ^ (llo & 7)) << 3);
    const int sw1 = sw0 ^ 32;

    const int lin = blockIdx.x;                 // 192 = 8 xcd x 24 chunks
    const int xcd = lin & 7, chunk = lin >> 3;
    const int bm = xcd * 2 + (chunk & 1);       // 0..15
    const int bn = chunk >> 1;                  // 0..11

    const __bf16* Ab = A  + (size_t)bm * 256 * 1024;
    const __bf16* Bb = Bt + (size_t)bn * 256 * 1024;

    v4f acc[8][4];
    #pragma unroll
    for (int fr = 0; fr < 8; ++fr)
        #pragma unroll
        for (int fc = 0; fc < 4; ++fc)
            #pragma unroll
            for (int r = 0; r < 4; ++r) acc[fr][fc][r] = 0.f;

    // -------- prologue: tile0 fully (4 halves) + tile1 A0,A1,B0 (3 halves) = 14 loads/thread
    stage_half(Ab, (__bf16*)As[0], 0, 0, tid);
    stage_half(Ab, (__bf16*)As[0], 1, 0, tid);
    stage_half(Bb, (__bf16*)Bs[0], 0, 0, tid);
    stage_half(Bb, (__bf16*)Bs[0], 1, 0, tid);
    stage_half(Ab, (__bf16*)As[1], 0, 64, tid);
    stage_half(Ab, (__bf16*)As[1], 1, 64, tid);
    stage_half(Bb, (__bf16*)Bs[1], 0, 64, tid);

    #pragma unroll 1
    for (int t = 0; t < 16; ++t) {
        const __bf16* Ap = As[t & 1];
        const __bf16* Bp = Bs[t & 1];
        __bf16* Anx = (__bf16*)As[(t & 1) ^ 1];
        __bf16* Bnx = (__bf16*)Bs[(t & 1) ^ 1];
        const int knx = (t + 1) << 6;

        // ---- tile boundary: stage first half of t+1, gate tile t landed, barrier ----
        if (t == 0) {
            stage_half(Bb, Bnx, 1, knx, tid);                    // tile1 B1 (last remaining)
            asm volatile("s_waitcnt vmcnt(8)" ::: "memory");     // drain tile0 (8 oldest)
        } else if (t < 15) {
            stage_half(Ab, Anx, 0, knx, tid);                    // tile t+1 A-half0
            asm volatile("s_waitcnt vmcnt(2)" ::: "memory");     // drain tile t (8 oldest)
        } else {
            asm volatile("s_waitcnt vmcnt(0)" ::: "memory");     // last tile: drain all
        }
        __builtin_amdgcn_sched_barrier(0);
        wg_barrier();                                            // cur tile visible to all

        // ---- phase 0: read B frags (8) + A quad0 (4) BEFORE barrier; stage A1(t+1) ----
        v8bf bfr[4][2];
        #pragma unroll
        for (int fc = 0; fc < 4; ++fc) {
            const int brow = wn * 64 + fc * 16 + llo;
            bfr[fc][0] = *(const v8bf*)&Bp[brow * 64 + sw0];
            bfr[fc][1] = *(const v8bf*)&Bp[brow * 64 + sw1];
        }
        {
            v8bf afr[2][2];
            #pragma unroll
            for (int i = 0; i < 2; ++i) {
                const int arow = wm * 128 + i * 16 + llo;
                afr[i][0] = *(const v8bf*)&Ap[arow * 64 + sw0];
                afr[i][1] = *(const v8bf*)&Ap[arow * 64 + sw1];
            }
            if (t >= 1 && t < 15) stage_half(Ab, Anx, 1, knx, tid);
            wg_barrier();
            __builtin_amdgcn_s_setprio(1);
            #pragma unroll
            for (int i = 0; i < 2; ++i)
                #pragma unroll
                for (int fc = 0; fc < 4; ++fc) {
                    acc[i][fc] = bf_mfma(afr[i][0], bfr[fc][0], acc[i][fc]);
                    acc[i][fc] = bf_mfma(afr[i][1], bfr[fc][1], acc[i][fc]);
                }
            __builtin_amdgcn_s_setprio(0);
            wg_barrier();
        }

        // ---- phases 1..3: read A quad q BEFORE barrier; stage B0/B1 of t+1 ----
        #pragma unroll
        for (int q = 1; q < 4; ++q) {
            v8bf afr[2][2];
            #pragma unroll
            for (int i = 0; i < 2; ++i) {
                const int arow = wm * 128 + (q * 2 + i) * 16 + llo;
                afr[i][0] = *(const v8bf*)&Ap[arow * 64 + sw0];
                afr[i][1] = *(const v8bf*)&Ap[arow * 64 + sw1];
            }
            if (t >= 1 && t < 15) {
                if (q == 1)      stage_half(Bb, Bnx, 0, knx, tid);
                else if (q == 2) stage_half(Bb, Bnx, 1, knx, tid);
            }
            wg_barrier();
            __builtin_amdgcn_s_setprio(1);
            #pragma unroll
            for (int i = 0; i < 2; ++i)
                #pragma unroll
                for (int fc = 0; fc < 4; ++fc) {
                    acc[q * 2 + i][fc] = bf_mfma(afr[i][0], bfr[fc][0], acc[q * 2 + i][fc]);
                    acc[q * 2 + i][fc] = bf_mfma(afr[i][1], bfr[fc][1], acc[q * 2 + i][fc]);
                }
            __builtin_amdgcn_s_setprio(0);
            wg_barrier();
        }
    }

    // ---------- epilogue (validated in r4) ----------
    const int row0 = bm * 256 + wm * 128;
    const int col0 = bn * 256 + wn * 64;
    if (col0 < 2048) {   // Q / K region (bn 0..7)
        #pragma unroll
        for (int fr = 0; fr < 8; ++fr) {
            const int rbase = row0 + fr * 16 + lhi * 4;
            #pragma unroll
            for (int fc = 0; fc < 4; ++fc) {
                const int c = col0 + fc * 16 + llo;
                #pragma unroll
                for (int r = 0; r < 4; ++r)
                    qk_out[(size_t)(rbase + r) * 2048 + c] = (__bf16)acc[fr][fc][r];
            }
        }
    } else {             // V region (bn 8..11) -> vt[(b*16+h)*64+s][t]
        #pragma unroll
        for (int fr = 0; fr < 8; ++fr) {
            const int rbase = row0 + fr * 16 + lhi * 4;
            const int bidx = rbase >> 10, t0 = rbase & 1023;
            #pragma unroll
            for (int fc = 0; fc < 4; ++fc) {
                const int c = col0 + fc * 16 + llo - 2048;
                v4bf pk;
                #pragma unroll
                for (int r = 0; r < 4; ++r) pk[r] = (__bf16)acc[fr][fc][r];
                *(v4bf*)&vt_out[((size_t)(bidx * NH + (c >> 6)) * HS + (c & 63)) * TT + t0] = pk;
            }
        }
    }
}

// -------- out-proj GEMM: 64x128 tiles, dbuf -> 512 blocks (r12-validated) --------
__global__ __launch_bounds__(256) void gemm_bt64_kernel(
    const __bf16* __restrict__ A, const __bf16* __restrict__ Bt, int K,
    float* __restrict__ f_out, const float* __restrict__ bias)
{
    __shared__ __align__(16) __bf16 As[2][64 * 64];
    __shared__ __align__(16) __bf16 Bs[2][128 * 64];
    const int tid = threadIdx.x;
    const int w = tid >> 6, l = tid & 63;
    const int wm = w & 1, wn = w >> 1;
    const int lhi = l >> 4, llo = l & 15;
    const int sw0 = ((lhi ^ (llo & 7)) << 3);
    const int sw1 = sw0 ^ 32;

    const int lin = blockIdx.x;
    const int xcd = lin & 7, j = lin >> 3;
    const int bm = xcd * 8 + (j & 7);
    const int bn = j >> 3;

    v4f acc[2][4];
    #pragma unroll
    for (int i = 0; i < 2; ++i)
        #pragma unroll
        for (int jj = 0; jj < 4; ++jj)
            #pragma unroll
            for (int r = 0; r < 4; ++r) acc[i][jj][r] = 0.f;

    const __bf16* Ab = A  + (size_t)bm * 64 * K;
    const __bf16* Bb = Bt + (size_t)bn * 128 * K;

    const int niter = K >> 6;
    {
        #pragma unroll
        for (int i = 0; i < 2; ++i) {
            int p = i * 256 + tid, row = p >> 3, lc = (p & 7) ^ (row & 7);
            gl_lds16(Ab + (size_t)row * K + lc * 8, As[0] + p * 8);
        }
        #pragma unroll
        for (int i = 0; i < 4; ++i) {
            int p = i * 256 + tid, row = p >> 3, lc = (p & 7) ^ (row & 7);
            gl_lds16(Bb + (size_t)row * K + lc * 8, Bs[0] + p * 8);
        }
    }

    for (int it = 0; it < niter; ++it) {
        const int buf = it & 1;
        __syncthreads();
        if (it + 1 < niter) {
            const int k0 = (it + 1) * 64;
            #pragma unroll
            for (int i = 0; i < 2; ++i) {
                int p = i * 256 + tid, row = p >> 3, lc = (p & 7) ^ (row & 7);
                gl_lds16(Ab + (size_t)row * K + k0 + lc * 8, As[buf ^ 1] + p * 8);
            }
            #pragma unroll
            for (int i = 0; i < 4; ++i) {
                int p = i * 256 + tid, row = p >> 3, lc = (p & 7) ^ (row & 7);
                gl_lds16(Bb + (size_t)row * K + k0 + lc * 8, Bs[buf ^ 1] + p * 8);
            }
        }
        #pragma unroll
        for (int kk = 0; kk < 64; kk += 32) {
            const int sw = kk ? sw1 : sw0;
            v8bf a[2], b[4];
            #pragma unroll
            for (int i = 0; i < 2; ++i)
                a[i] = *(const v8bf*)&As[buf][(wm * 32 + i * 16 + llo) * 64 + sw];
            #pragma unroll
            for (int jj = 0; jj < 4; ++jj)
                b[jj] = *(const v8bf*)&Bs[buf][(wn * 64 + jj * 16 + llo) * 64 + sw];
            #pragma unroll
            for (int i = 0; i < 2; ++i)
                #pragma unroll
                for (int jj = 0; jj < 4; ++jj)
                    acc[i][jj] = __builtin_amdgcn_mfma_f32_16x16x32_bf16(a[i], b[jj], acc[i][jj], 0, 0, 0);
        }
    }

    const int row0 = bm * 64 + wm * 32;
    const int col0 = bn * 128 + wn * 64;
    #pragma unroll
    for (int jj = 0; jj < 4; ++jj) {
        int c = col0 + jj * 16 + llo;
        float bv = bias[c];
        #pragma unroll
        for (int i = 0; i < 2; ++i) {
            int rbase = row0 + i * 16 + lhi * 4;
            #pragma unroll
            for (int r = 0; r < 4; ++r)
                f_out[(size_t)(rbase + r) * DE + c] = acc[i][jj][r] + bv;
        }
    }
}

// ---------------- flash attention v7 (kept): dbuf staging + XOR swizzle, 40KB LDS (4/CU),
// balanced perm'd supertile map ----------------
__device__ __forceinline__ void stage_kv(
    const __bf16* __restrict__ kb, const __bf16* __restrict__ vb,
    __bf16* Ksb, __bf16* Vsb, int k0, int tid)
{
    #pragma unroll
    for (int i = 0; i < 2; ++i) {
        int p   = i * 256 + tid;
        int row = p >> 3;
        int lc  = (p & 7) ^ (row & 7);
        gl_lds16(kb + (size_t)(k0 + row) * 2048 + lc * 8, Ksb + p * 8);
        gl_lds16(vb + (size_t)row * TT + k0 + lc * 8,     Vsb + p * 8);
    }
}

template<bool DIAG>
__device__ __forceinline__ void attn_compute(
    const __bf16* __restrict__ Ksb, const __bf16* __restrict__ Vsb,
    __bf16* __restrict__ PsW, int k0, int r0, int lhi, int llo, int sw0, int sw1,
    v8bf aq0, v8bf aq1, v4f (&o)[4], float (&l_part)[4])
{
    v4f sacc[4];
    #pragma unroll
    for (int n = 0; n < 4; ++n)
        #pragma unroll
        for (int r = 0; r < 4; ++r) sacc[n][r] = 0.f;
    #pragma unroll
    for (int n = 0; n < 4; ++n) {
        v8bf bk0 = *(const v8bf*)&Ksb[(n * 16 + llo) * 64 + sw0];
        v8bf bk1 = *(const v8bf*)&Ksb[(n * 16 + llo) * 64 + sw1];
        sacc[n] = bf_mfma(aq0, bk0, sacc[n]);
        sacc[n] = bf_mfma(aq1, bk1, sacc[n]);
    }

    float prob[4][4];
    #pragma unroll
    for (int n = 0; n < 4; ++n) {
        int colg = k0 + n * 16 + llo;
        #pragma unroll
        for (int r = 0; r < 4; ++r) {
            float s2 = sacc[n][r] * 0.18033688f;   // 0.125 * log2(e)
            if (DIAG) { int rowg = r0 + lhi * 4 + r; if (colg > rowg) s2 = -1e30f; }
            float p = exp2f(s2);
            prob[n][r] = p;
            l_part[r] += p;
        }
    }

    // P store: [16][64] with granule swizzle g' = g ^ (row&7)
    #pragma unroll
    for (int r = 0; r < 4; ++r) {
        int prow = lhi * 4 + r;
        #pragma unroll
        for (int n = 0; n < 4; ++n) {
            int g = (n * 2 + (llo >> 3)) ^ (prow & 7);
            PsW[prow * 64 + g * 8 + (llo & 7)] = (__bf16)prob[n][r];
        }
    }

    #pragma unroll
    for (int kk = 0; kk < 64; kk += 32) {
        v8bf ap = *(const v8bf*)&PsW[llo * 64 + (((kk >> 3) + lhi) ^ (llo & 7)) * 8];
        const int sw = kk ? sw1 : sw0;
        #pragma unroll
        for (int n = 0; n < 4; ++n) {
            v8bf bv = *(const v8bf*)&Vsb[(n * 16 + llo) * 64 + sw];
            o[n] = bf_mfma(ap, bv, o[n]);
        }
    }
}

__global__ __launch_bounds__(256) void attn_kernel(
    const __bf16* __restrict__ qk, const __bf16* __restrict__ vt,
    __bf16* __restrict__ att)
{
    __shared__ __align__(16) __bf16 Ks[2][64 * 64];
    __shared__ __align__(16) __bf16 Vs[2][64 * 64];
    __shared__ __align__(16) __bf16 Ps[4][16 * 64];   // 8KB; block total 40KB = 4 blocks/CU

    const int tid = threadIdx.x;
    const int w = tid >> 6, l = tid & 63;
    const int lhi = l >> 4, llo = l & 15;
    const int sw0 = ((lhi ^ (llo & 7)) << 3);
    const int sw1 = sw0 ^ 32;
    const int bh = blockIdx.x & 63;          // same-bh blocks 64 apart -> same XCD
    const int k = blockIdx.x >> 6;
    const int qt = (k & 4) ? (k >= 12 ? k - 12 : k + 4) : (15 - k);
    const int b = bh >> 4, h = bh & 15;

    const __bf16* qbase = qk + (size_t)b * TT * 2048 + h * HS;
    const __bf16* kbase = qk + (size_t)b * TT * 2048 + 1024 + h * HS;
    const __bf16* vbase = vt + (size_t)bh * HS * TT;
    __bf16* PsW = &Ps[w][0];

    const int r0 = qt * 64 + w * 16;

    stage_kv(kbase, vbase, Ks[0], Vs[0], 0, tid);

    v8bf aq0 = *(const v8bf*)&qbase[(size_t)(r0 + llo) * 2048 + lhi * 8];
    v8bf aq1 = *(const v8bf*)&qbase[(size_t)(r0 + llo) * 2048 + 32 + lhi * 8];

    float l_part[4] = {0.f, 0.f, 0.f, 0.f};
    v4f o[4];
    #pragma unroll
    for (int n = 0; n < 4; ++n)
        #pragma unroll
        for (int r = 0; r < 4; ++r) o[n][r] = 0.f;

    for (int kt = 0; kt < qt; ++kt) {
        const int buf = kt & 1;
        __syncthreads();
        stage_kv(kbase, vbase, Ks[buf ^ 1], Vs[buf ^ 1], (kt + 1) * 64, tid);
        attn_compute<false>(Ks[buf], Vs[buf], PsW, kt * 64, r0, lhi, llo, sw0, sw1, aq0, aq1, o, l_part);
    }
    __syncthreads();
    attn_compute<true>(Ks[qt & 1], Vs[qt & 1], PsW, qt * 64, r0, lhi, llo, sw0, sw1, aq0, aq1, o, l_part);

    #pragma unroll
    for (int r = 0; r < 4; ++r) {
        float s = l_part[r];
        #pragma unroll
        for (int msk = 1; msk < 16; msk <<= 1) s += __shfl_xor(s, msk, 64);
        float inv = 1.f / s;
        int rowg = b * TT + r0 + lhi * 4 + r;
        #pragma unroll
        for (int n = 0; n < 4; ++n)
            att[(size_t)rowg * DE + h * HS + n * 16 + llo] = (__bf16)(o[n][r] * inv);
    }
}

extern "C" void kernel_launch(void* const* d_in, const int* in_sizes, int n_in,
                              void* d_out, int out_size, void* d_ws, size_t ws_size,
                              hipStream_t stream)
{
    const float* x  = (const float*)d_in[0];
    const float* Wq = (const float*)d_in[1];
    const float* Wk = (const float*)d_in[2];
    const float* Wv = (const float*)d_in[3];
    const float* Wo = (const float*)d_in[4];
    const float* bo = (const float*)d_in[5];
    float* out = (float*)d_out;

    char* ws = (char*)d_ws;
    __bf16* xb  = (__bf16*)(ws);                 // 8 MB   [4096][1024]
    __bf16* Wt  = (__bf16*)(ws + 8388608);       // 6 MB   [3072][1024]
    __bf16* Wob = (__bf16*)(ws + 14680064);      // 2 MB   [1024][1024]
    __bf16* qk  = (__bf16*)(ws + 16777216);      // 16 MB  [4096][2048]
    __bf16* vt  = (__bf16*)(ws + 33554432);      // 8 MB   [64][64][1024]
    __bf16* att = (__bf16*)(ws + 41943040);      // 8 MB   [4096][1024]

    // fused prep: casts (5120 blocks) + weight transpose (768 blocks)
    prep_all_kernel<<<5888, 256, 0, stream>>>(x, xb, Wo, Wob, Wq, Wk, Wv, Wt);
    // QKV: M=4096, N=3072, K=1024 -> 192 blocks of 256x256, 8-phase reads-before-barrier
    gemm_qkv_8ph<<<192, 512, 0, stream>>>(xb, Wt, qk, vt);
    // attention: 1024 blocks = 64 bh x 16 q-supertiles, 4 blocks/CU, balanced perm map
    attn_kernel<<<1024, 256, 0, stream>>>(qk, vt, att);
    // out proj: M=4096, N=1024, K=1024 -> 512 blocks (8 xcd x 8 bm x 8 bn), 64x128 tiles
    gemm_bt64_kernel<<<512, 256, 0, stream>>>(att, Wob, 1024, out, bo);
}

// Round 6
// 158.306 us; speedup vs baseline: 1.0698x; 1.0698x over previous
//
#include <hip/hip_runtime.h>
#include <hip/hip_bf16.h>
#include <math.h>

#define NH 16
#define HS 64
#define DE 1024
#define TT 1024
#define BBATCH 4
#define MTOK 4096   // B*T

typedef __bf16 v8bf __attribute__((ext_vector_type(8)));
typedef __bf16 v4bf __attribute__((ext_vector_type(4)));
typedef float  v4f  __attribute__((ext_vector_type(4)));

__device__ __forceinline__ void gl_lds16(const __bf16* g, __bf16* l) {
    __builtin_amdgcn_global_load_lds(
        (const __attribute__((address_space(1))) unsigned int*)g,
        (__attribute__((address_space(3))) unsigned int*)l, 16, 0, 0);
}

__device__ __forceinline__ v4f bf_mfma(v8bf a, v8bf b, v4f c) {
    return __builtin_amdgcn_mfma_f32_16x16x32_bf16(a, b, c, 0, 0, 0);
}

__device__ __forceinline__ void wg_barrier() {
    asm volatile("" ::: "memory");
    __builtin_amdgcn_s_barrier();
    asm volatile("" ::: "memory");
}

// ---------------- fused prep: cast x (1048576 f4), cast Wo (262144 f4), transpose Wq/Wk/Wv ----
__global__ __launch_bounds__(256) void prep_all_kernel(
    const float* __restrict__ x,  __bf16* __restrict__ xb,
    const float* __restrict__ Wo, __bf16* __restrict__ Wob,
    const float* __restrict__ Wq, const float* __restrict__ Wk,
    const float* __restrict__ Wv, __bf16* __restrict__ Wt)
{
    const int bid = blockIdx.x;
    const int t = threadIdx.x;
    if (bid < 5120) {
        int i = bid * 256 + t;
        const float* in; __bf16* out;
        if (i < 1048576) { in = x;  out = xb; }
        else             { in = Wo; out = Wob; i -= 1048576; }
        float4 v = ((const float4*)in)[i];
        v4bf o;
        o[0] = (__bf16)v.x; o[1] = (__bf16)v.y; o[2] = (__bf16)v.z; o[3] = (__bf16)v.w;
        *(v4bf*)&out[(size_t)i * 4] = o;
        return;
    }
    const int bid2 = bid - 5120;
    const int c0 = (bid2 & 15) * 64, h = (bid2 >> 4) & 15, m = bid2 >> 8;
    const float* W = (m == 0) ? Wq : (m == 1) ? Wk : Wv;
    __shared__ float tile[64][65];
    #pragma unroll
    for (int pp = 0; pp < 16; ++pp) {
        int cl = pp * 4 + (t >> 6);
        int s  = t & 63;
        tile[cl][s] = W[((size_t)h * DE + c0 + cl) * HS + s];
    }
    __syncthreads();
    #pragma unroll
    for (int pp = 0; pp < 16; ++pp) {
        int s  = pp * 4 + (t >> 6);
        int cl = t & 63;
        Wt[((size_t)(m * DE + h * HS + s)) * DE + c0 + cl] = (__bf16)tile[cl][s];
    }
}

// -------- QKV GEMM (reverted to m97 structure): 128x128, SINGLE-buffer 2-barrier K-loop
// (32KB LDS -> 3 blocks/CU, whole 768-block grid co-resident) + XCD swizzle + XOR swizzle ----
__device__ __forceinline__ void gemm_stage(
    const __bf16* __restrict__ Ab, const __bf16* __restrict__ Bb,
    __bf16* As, __bf16* Bs, int K, int k0, int w, int l)
{
    #pragma unroll
    for (int i = 0; i < 4; ++i) {
        int p   = i * 256 + w * 64 + l;
        int row = p >> 3;
        int lc  = (p & 7) ^ (row & 7);
        gl_lds16(Ab + (size_t)row * K + k0 + lc * 8, As + p * 8);
        gl_lds16(Bb + (size_t)row * K + k0 + lc * 8, Bs + p * 8);
    }
}

__global__ __launch_bounds__(256) void gemm_bt_kernel(
    const __bf16* __restrict__ A, const __bf16* __restrict__ Bt,
    int K,
    __bf16* __restrict__ qk_out, __bf16* __restrict__ vt_out)
{
    __shared__ __align__(16) __bf16 As[128 * 64];
    __shared__ __align__(16) __bf16 Bs[128 * 64];
    const int tid = threadIdx.x;
    const int w = tid >> 6, l = tid & 63;
    const int wm = w >> 1, wn = w & 1;
    const int lhi = l >> 4, llo = l & 15;
    const int sw0 = ((lhi ^ (llo & 7)) << 3);
    const int sw1 = sw0 ^ 32;

    const int lin = blockIdx.x;
    const int xcd = lin & 7, j = lin >> 3;
    const int bm = xcd * 4 + (j & 3);
    const int bn = j >> 2;

    v4f acc[4][4];
    #pragma unroll
    for (int i = 0; i < 4; ++i)
        #pragma unroll
        for (int jj = 0; jj < 4; ++jj)
            #pragma unroll
            for (int r = 0; r < 4; ++r) acc[i][jj][r] = 0.f;

    const __bf16* Ab = A  + (size_t)bm * 128 * K;
    const __bf16* Bb = Bt + (size_t)bn * 128 * K;

    const int niter = K >> 6;
    for (int it = 0; it < niter; ++it) {
        if (it) __syncthreads();               // all waves done reading previous tile
        gemm_stage(Ab, Bb, As, Bs, K, it * 64, w, l);
        __syncthreads();                       // drain gl_lds for this tile
        #pragma unroll
        for (int kk = 0; kk < 64; kk += 32) {
            const int sw = kk ? sw1 : sw0;
            v8bf a[4], b[4];
            #pragma unroll
            for (int i = 0; i < 4; ++i)
                a[i] = *(const v8bf*)&As[(wm * 64 + i * 16 + llo) * 64 + sw];
            #pragma unroll
            for (int jj = 0; jj < 4; ++jj)
                b[jj] = *(const v8bf*)&Bs[(wn * 64 + jj * 16 + llo) * 64 + sw];
            #pragma unroll
            for (int i = 0; i < 4; ++i)
                #pragma unroll
                for (int jj = 0; jj < 4; ++jj)
                    acc[i][jj] = __builtin_amdgcn_mfma_f32_16x16x32_bf16(a[i], b[jj], acc[i][jj], 0, 0, 0);
        }
    }

    const int row0 = bm * 128 + wm * 64;
    const int col0 = bn * 128 + wn * 64;

    if (col0 < 2048) {   // Q / K region
        #pragma unroll
        for (int i = 0; i < 4; ++i) {
            int rbase = row0 + i * 16 + lhi * 4;
            #pragma unroll
            for (int jj = 0; jj < 4; ++jj) {
                int c = col0 + jj * 16 + llo;
                #pragma unroll
                for (int r = 0; r < 4; ++r)
                    qk_out[(size_t)(rbase + r) * 2048 + c] = (__bf16)acc[i][jj][r];
            }
        }
    } else {             // V region -> vt[(b*16+h)*64+s][t]
        #pragma unroll
        for (int i = 0; i < 4; ++i) {
            int rbase = row0 + i * 16 + lhi * 4;
            int bidx = rbase >> 10, t0 = rbase & 1023;
            #pragma unroll
            for (int jj = 0; jj < 4; ++jj) {
                int c = col0 + jj * 16 + llo - 2048;
                v4bf pk;
                #pragma unroll
                for (int r = 0; r < 4; ++r) pk[r] = (__bf16)acc[i][jj][r];
                *(v4bf*)&vt_out[((size_t)(bidx * NH + (c >> 6)) * HS + (c & 63)) * TT + t0] = pk;
            }
        }
    }
}

// ======== out-proj GEMM v2: 128x128 tiles, 256 blocks (1/CU, all co-resident), T3-minimum
// 2-phase dbuf: {STAGE(t+1,buf^1) -> compute(t,buf) -> vmcnt(0) -> raw barrier}. One barrier
// per K-tile; stage issued a full tile ahead; QKV-proven 4x4-acc inner loop (32 MFMA:16 reads).
__device__ __forceinline__ void op_stage(
    const __bf16* __restrict__ Ab, const __bf16* __restrict__ Bb,
    __bf16* As, __bf16* Bs, int k0, int tid)
{
    #pragma unroll
    for (int i = 0; i < 4; ++i) {
        int p   = i * 256 + tid;
        int row = p >> 3;
        int lc  = (p & 7) ^ (row & 7);
        gl_lds16(Ab + (size_t)row * 1024 + k0 + lc * 8, As + p * 8);
        gl_lds16(Bb + (size_t)row * 1024 + k0 + lc * 8, Bs + p * 8);
    }
}

__global__ __launch_bounds__(256) void gemm_op128_kernel(
    const __bf16* __restrict__ A, const __bf16* __restrict__ Bt,
    float* __restrict__ f_out, const float* __restrict__ bias)
{
    __shared__ __align__(16) __bf16 As[2][128 * 64];
    __shared__ __align__(16) __bf16 Bs[2][128 * 64];
    const int tid = threadIdx.x;
    const int w = tid >> 6, l = tid & 63;
    const int wm = w >> 1, wn = w & 1;
    const int lhi = l >> 4, llo = l & 15;
    const int sw0 = ((lhi ^ (llo & 7)) << 3);
    const int sw1 = sw0 ^ 32;

    const int lin = blockIdx.x;                 // 256 = 8 xcd x 32
    const int xcd = lin & 7, j = lin >> 3;
    const int bm = xcd * 4 + (j & 3);           // 0..31 ; per XCD: 4 A-panels (1MB) + all of B (2MB) in L2
    const int bn = j >> 2;                      // 0..7

    v4f acc[4][4];
    #pragma unroll
    for (int i = 0; i < 4; ++i)
        #pragma unroll
        for (int jj = 0; jj < 4; ++jj)
            #pragma unroll
            for (int r = 0; r < 4; ++r) acc[i][jj][r] = 0.f;

    const __bf16* Ab = A  + (size_t)bm * 128 * 1024;
    const __bf16* Bb = Bt + (size_t)bn * 128 * 1024;

    // prologue: stage tile 0, drain, barrier
    op_stage(Ab, Bb, (__bf16*)As[0], (__bf16*)Bs[0], 0, tid);
    asm volatile("s_waitcnt vmcnt(0)" ::: "memory");
    __builtin_amdgcn_sched_barrier(0);
    wg_barrier();

    #pragma unroll 1
    for (int t = 0; t < 16; ++t) {
        const int cur = t & 1;
        // stage next tile FIRST (buf^1 was last read in iter t-1, all waves passed that barrier)
        if (t < 15)
            op_stage(Ab, Bb, (__bf16*)As[cur ^ 1], (__bf16*)Bs[cur ^ 1], (t + 1) * 64, tid);

        // compute current tile (compiler emits fine-grained lgkmcnt before MFMAs)
        #pragma unroll
        for (int kk = 0; kk < 64; kk += 32) {
            const int sw = kk ? sw1 : sw0;
            v8bf a[4], b[4];
            #pragma unroll
            for (int i = 0; i < 4; ++i)
                a[i] = *(const v8bf*)&As[cur][(wm * 64 + i * 16 + llo) * 64 + sw];
            #pragma unroll
            for (int jj = 0; jj < 4; ++jj)
                b[jj] = *(const v8bf*)&Bs[cur][(wn * 64 + jj * 16 + llo) * 64 + sw];
            __builtin_amdgcn_s_setprio(1);
            #pragma unroll
            for (int i = 0; i < 4; ++i)
                #pragma unroll
                for (int jj = 0; jj < 4; ++jj)
                    acc[i][jj] = bf_mfma(a[i], b[jj], acc[i][jj]);
            __builtin_amdgcn_s_setprio(0);
        }

        // drain next-tile loads (they flew during compute) + barrier
        if (t < 15) {
            asm volatile("s_waitcnt vmcnt(0)" ::: "memory");
            __builtin_amdgcn_sched_barrier(0);
            wg_barrier();
        }
    }

    const int row0 = bm * 128 + wm * 64;
    const int col0 = bn * 128 + wn * 64;
    #pragma unroll
    for (int jj = 0; jj < 4; ++jj) {
        int c = col0 + jj * 16 + llo;
        float bv = bias[c];
        #pragma unroll
        for (int i = 0; i < 4; ++i) {
            int rbase = row0 + i * 16 + lhi * 4;
            #pragma unroll
            for (int r = 0; r < 4; ++r)
                f_out[(size_t)(rbase + r) * DE + c] = acc[i][jj][r] + bv;
        }
    }
}

// ---------------- flash attention v7 (kept): dbuf staging + XOR swizzle, 40KB LDS (4/CU),
// balanced perm'd supertile map ----------------
__device__ __forceinline__ void stage_kv(
    const __bf16* __restrict__ kb, const __bf16* __restrict__ vb,
    __bf16* Ksb, __bf16* Vsb, int k0, int tid)
{
    #pragma unroll
    for (int i = 0; i < 2; ++i) {
        int p   = i * 256 + tid;
        int row = p >> 3;
        int lc  = (p & 7) ^ (row & 7);
        gl_lds16(kb + (size_t)(k0 + row) * 2048 + lc * 8, Ksb + p * 8);
        gl_lds16(vb + (size_t)row * TT + k0 + lc * 8,     Vsb + p * 8);
    }
}

template<bool DIAG>
__device__ __forceinline__ void attn_compute(
    const __bf16* __restrict__ Ksb, const __bf16* __restrict__ Vsb,
    __bf16* __restrict__ PsW, int k0, int r0, int lhi, int llo, int sw0, int sw1,
    v8bf aq0, v8bf aq1, v4f (&o)[4], float (&l_part)[4])
{
    v4f sacc[4];
    #pragma unroll
    for (int n = 0; n < 4; ++n)
        #pragma unroll
        for (int r = 0; r < 4; ++r) sacc[n][r] = 0.f;
    #pragma unroll
    for (int n = 0; n < 4; ++n) {
        v8bf bk0 = *(const v8bf*)&Ksb[(n * 16 + llo) * 64 + sw0];
        v8bf bk1 = *(const v8bf*)&Ksb[(n * 16 + llo) * 64 + sw1];
        sacc[n] = bf_mfma(aq0, bk0, sacc[n]);
        sacc[n] = bf_mfma(aq1, bk1, sacc[n]);
    }

    float prob[4][4];
    #pragma unroll
    for (int n = 0; n < 4; ++n) {
        int colg = k0 + n * 16 + llo;
        #pragma unroll
        for (int r = 0; r < 4; ++r) {
            float s2 = sacc[n][r] * 0.18033688f;   // 0.125 * log2(e)
            if (DIAG) { int rowg = r0 + lhi * 4 + r; if (colg > rowg) s2 = -1e30f; }
            float p = exp2f(s2);
            prob[n][r] = p;
            l_part[r] += p;
        }
    }

    // P store: [16][64] with granule swizzle g' = g ^ (row&7)
    #pragma unroll
    for (int r = 0; r < 4; ++r) {
        int prow = lhi * 4 + r;
        #pragma unroll
        for (int n = 0; n < 4; ++n) {
            int g = (n * 2 + (llo >> 3)) ^ (prow & 7);
            PsW[prow * 64 + g * 8 + (llo & 7)] = (__bf16)prob[n][r];
        }
    }

    #pragma unroll
    for (int kk = 0; kk < 64; kk += 32) {
        v8bf ap = *(const v8bf*)&PsW[llo * 64 + (((kk >> 3) + lhi) ^ (llo & 7)) * 8];
        const int sw = kk ? sw1 : sw0;
        #pragma unroll
        for (int n = 0; n < 4; ++n) {
            v8bf bv = *(const v8bf*)&Vsb[(n * 16 + llo) * 64 + sw];
            o[n] = bf_mfma(ap, bv, o[n]);
        }
    }
}

__global__ __launch_bounds__(256) void attn_kernel(
    const __bf16* __restrict__ qk, const __bf16* __restrict__ vt,
    __bf16* __restrict__ att)
{
    __shared__ __align__(16) __bf16 Ks[2][64 * 64];
    __shared__ __align__(16) __bf16 Vs[2][64 * 64];
    __shared__ __align__(16) __bf16 Ps[4][16 * 64];   // 8KB; block total 40KB = 4 blocks/CU

    const int tid = threadIdx.x;
    const int w = tid >> 6, l = tid & 63;
    const int lhi = l >> 4, llo = l & 15;
    const int sw0 = ((lhi ^ (llo & 7)) << 3);
    const int sw1 = sw0 ^ 32;
    const int bh = blockIdx.x & 63;          // same-bh blocks 64 apart -> same XCD
    const int k = blockIdx.x >> 6;
    const int qt = (k & 4) ? (k >= 12 ? k - 12 : k + 4) : (15 - k);
    const int b = bh >> 4, h = bh & 15;

    const __bf16* qbase = qk + (size_t)b * TT * 2048 + h * HS;
    const __bf16* kbase = qk + (size_t)b * TT * 2048 + 1024 + h * HS;
    const __bf16* vbase = vt + (size_t)bh * HS * TT;
    __bf16* PsW = &Ps[w][0];

    const int r0 = qt * 64 + w * 16;

    stage_kv(kbase, vbase, Ks[0], Vs[0], 0, tid);

    v8bf aq0 = *(const v8bf*)&qbase[(size_t)(r0 + llo) * 2048 + lhi * 8];
    v8bf aq1 = *(const v8bf*)&qbase[(size_t)(r0 + llo) * 2048 + 32 + lhi * 8];

    float l_part[4] = {0.f, 0.f, 0.f, 0.f};
    v4f o[4];
    #pragma unroll
    for (int n = 0; n < 4; ++n)
        #pragma unroll
        for (int r = 0; r < 4; ++r) o[n][r] = 0.f;

    for (int kt = 0; kt < qt; ++kt) {
        const int buf = kt & 1;
        __syncthreads();
        stage_kv(kbase, vbase, Ks[buf ^ 1], Vs[buf ^ 1], (kt + 1) * 64, tid);
        attn_compute<false>(Ks[buf], Vs[buf], PsW, kt * 64, r0, lhi, llo, sw0, sw1, aq0, aq1, o, l_part);
    }
    __syncthreads();
    attn_compute<true>(Ks[qt & 1], Vs[qt & 1], PsW, qt * 64, r0, lhi, llo, sw0, sw1, aq0, aq1, o, l_part);

    #pragma unroll
    for (int r = 0; r < 4; ++r) {
        float s = l_part[r];
        #pragma unroll
        for (int msk = 1; msk < 16; msk <<= 1) s += __shfl_xor(s, msk, 64);
        float inv = 1.f / s;
        int rowg = b * TT + r0 + lhi * 4 + r;
        #pragma unroll
        for (int n = 0; n < 4; ++n)
            att[(size_t)rowg * DE + h * HS + n * 16 + llo] = (__bf16)(o[n][r] * inv);
    }
}

extern "C" void kernel_launch(void* const* d_in, const int* in_sizes, int n_in,
                              void* d_out, int out_size, void* d_ws, size_t ws_size,
                              hipStream_t stream)
{
    const float* x  = (const float*)d_in[0];
    const float* Wq = (const float*)d_in[1];
    const float* Wk = (const float*)d_in[2];
    const float* Wv = (const float*)d_in[3];
    const float* Wo = (const float*)d_in[4];
    const float* bo = (const float*)d_in[5];
    float* out = (float*)d_out;

    char* ws = (char*)d_ws;
    __bf16* xb  = (__bf16*)(ws);                 // 8 MB   [4096][1024]
    __bf16* Wt  = (__bf16*)(ws + 8388608);       // 6 MB   [3072][1024]
    __bf16* Wob = (__bf16*)(ws + 14680064);      // 2 MB   [1024][1024]
    __bf16* qk  = (__bf16*)(ws + 16777216);      // 16 MB  [4096][2048]
    __bf16* vt  = (__bf16*)(ws + 33554432);      // 8 MB   [64][64][1024]
    __bf16* att = (__bf16*)(ws + 41943040);      // 8 MB   [4096][1024]

    // fused prep: casts (5120 blocks) + weight transpose (768 blocks)
    prep_all_kernel<<<5888, 256, 0, stream>>>(x, xb, Wo, Wob, Wq, Wk, Wv, Wt);
    // QKV (m97 revert): M=4096, N=3072, K=1024 -> 768 blocks, 3 blocks/CU co-resident
    gemm_bt_kernel<<<768, 256, 0, stream>>>(xb, Wt, 1024, qk, vt);
    // attention: 1024 blocks = 64 bh x 16 q-supertiles, 4 blocks/CU, balanced perm map
    attn_kernel<<<1024, 256, 0, stream>>>(qk, vt, att);
    // out proj v2: M=4096, N=1024, K=1024 -> 256 blocks of 128x128, 2-phase counted dbuf
    gemm_op128_kernel<<<256, 256, 0, stream>>>(att, Wob, out, bo);
}

// Round 7
// 157.603 us; speedup vs baseline: 1.0745x; 1.0045x over previous
//
#include <hip/hip_runtime.h>
#include <hip/hip_bf16.h>
#include <math.h>

#define NH 16
#define HS 64
#define DE 1024
#define TT 1024
#define BBATCH 4
#define MTOK 4096   // B*T

typedef __bf16 v8bf __attribute__((ext_vector_type(8)));
typedef __bf16 v4bf __attribute__((ext_vector_type(4)));
typedef float  v4f  __attribute__((ext_vector_type(4)));

__device__ __forceinline__ void gl_lds16(const __bf16* g, __bf16* l) {
    __builtin_amdgcn_global_load_lds(
        (const __attribute__((address_space(1))) unsigned int*)g,
        (__attribute__((address_space(3))) unsigned int*)l, 16, 0, 0);
}

// ---------------- fused prep: cast x (1048576 f4), cast Wo (262144 f4), transpose Wq/Wk/Wv ----
__global__ __launch_bounds__(256) void prep_all_kernel(
    const float* __restrict__ x,  __bf16* __restrict__ xb,
    const float* __restrict__ Wo, __bf16* __restrict__ Wob,
    const float* __restrict__ Wq, const float* __restrict__ Wk,
    const float* __restrict__ Wv, __bf16* __restrict__ Wt)
{
    const int bid = blockIdx.x;
    const int t = threadIdx.x;
    if (bid < 5120) {
        int i = bid * 256 + t;
        const float* in; __bf16* out;
        if (i < 1048576) { in = x;  out = xb; }
        else             { in = Wo; out = Wob; i -= 1048576; }
        float4 v = ((const float4*)in)[i];
        v4bf o;
        o[0] = (__bf16)v.x; o[1] = (__bf16)v.y; o[2] = (__bf16)v.z; o[3] = (__bf16)v.w;
        *(v4bf*)&out[(size_t)i * 4] = o;
        return;
    }
    const int bid2 = bid - 5120;
    const int c0 = (bid2 & 15) * 64, h = (bid2 >> 4) & 15, m = bid2 >> 8;
    const float* W = (m == 0) ? Wq : (m == 1) ? Wk : Wv;
    __shared__ float tile[64][65];
    #pragma unroll
    for (int pp = 0; pp < 16; ++pp) {
        int cl = pp * 4 + (t >> 6);
        int s  = t & 63;
        tile[cl][s] = W[((size_t)h * DE + c0 + cl) * HS + s];
    }
    __syncthreads();
    #pragma unroll
    for (int pp = 0; pp < 16; ++pp) {
        int s  = pp * 4 + (t >> 6);
        int cl = t & 63;
        Wt[((size_t)(m * DE + h * HS + s)) * DE + c0 + cl] = (__bf16)tile[cl][s];
    }
}

// -------- QKV GEMM: 128x128, SINGLE-buffer m97 2-barrier K-loop (32KB LDS -> 3 blocks/CU,
// whole 768-block grid co-resident, no tail) + XCD swizzle + XOR bank swizzle --------
__device__ __forceinline__ void gemm_stage(
    const __bf16* __restrict__ Ab, const __bf16* __restrict__ Bb,
    __bf16* As, __bf16* Bs, int K, int k0, int w, int l)
{
    #pragma unroll
    for (int i = 0; i < 4; ++i) {
        int p   = i * 256 + w * 64 + l;
        int row = p >> 3;
        int lc  = (p & 7) ^ (row & 7);
        gl_lds16(Ab + (size_t)row * K + k0 + lc * 8, As + p * 8);
        gl_lds16(Bb + (size_t)row * K + k0 + lc * 8, Bs + p * 8);
    }
}

__global__ __launch_bounds__(256) void gemm_bt_kernel(
    const __bf16* __restrict__ A, const __bf16* __restrict__ Bt,
    int K,
    __bf16* __restrict__ qk_out, __bf16* __restrict__ vt_out)
{
    __shared__ __align__(16) __bf16 As[128 * 64];
    __shared__ __align__(16) __bf16 Bs[128 * 64];
    const int tid = threadIdx.x;
    const int w = tid >> 6, l = tid & 63;
    const int wm = w >> 1, wn = w & 1;
    const int lhi = l >> 4, llo = l & 15;
    const int sw0 = ((lhi ^ (llo & 7)) << 3);
    const int sw1 = sw0 ^ 32;

    const int lin = blockIdx.x;
    const int xcd = lin & 7, j = lin >> 3;
    const int bm = xcd * 4 + (j & 3);
    const int bn = j >> 2;

    v4f acc[4][4];
    #pragma unroll
    for (int i = 0; i < 4; ++i)
        #pragma unroll
        for (int jj = 0; jj < 4; ++jj)
            #pragma unroll
            for (int r = 0; r < 4; ++r) acc[i][jj][r] = 0.f;

    const __bf16* Ab = A  + (size_t)bm * 128 * K;
    const __bf16* Bb = Bt + (size_t)bn * 128 * K;

    const int niter = K >> 6;
    for (int it = 0; it < niter; ++it) {
        if (it) __syncthreads();               // all waves done reading previous tile
        gemm_stage(Ab, Bb, As, Bs, K, it * 64, w, l);
        __syncthreads();                       // drain gl_lds for this tile
        #pragma unroll
        for (int kk = 0; kk < 64; kk += 32) {
            const int sw = kk ? sw1 : sw0;
            v8bf a[4], b[4];
            #pragma unroll
            for (int i = 0; i < 4; ++i)
                a[i] = *(const v8bf*)&As[(wm * 64 + i * 16 + llo) * 64 + sw];
            #pragma unroll
            for (int jj = 0; jj < 4; ++jj)
                b[jj] = *(const v8bf*)&Bs[(wn * 64 + jj * 16 + llo) * 64 + sw];
            #pragma unroll
            for (int i = 0; i < 4; ++i)
                #pragma unroll
                for (int jj = 0; jj < 4; ++jj)
                    acc[i][jj] = __builtin_amdgcn_mfma_f32_16x16x32_bf16(a[i], b[jj], acc[i][jj], 0, 0, 0);
        }
    }

    const int row0 = bm * 128 + wm * 64;
    const int col0 = bn * 128 + wn * 64;

    if (col0 < 2048) {   // Q / K region
        #pragma unroll
        for (int i = 0; i < 4; ++i) {
            int rbase = row0 + i * 16 + lhi * 4;
            #pragma unroll
            for (int jj = 0; jj < 4; ++jj) {
                int c = col0 + jj * 16 + llo;
                #pragma unroll
                for (int r = 0; r < 4; ++r)
                    qk_out[(size_t)(rbase + r) * 2048 + c] = (__bf16)acc[i][jj][r];
            }
        }
    } else {             // V region -> vt[(b*16+h)*64+s][t]
        #pragma unroll
        for (int i = 0; i < 4; ++i) {
            int rbase = row0 + i * 16 + lhi * 4;
            int bidx = rbase >> 10, t0 = rbase & 1023;
            #pragma unroll
            for (int jj = 0; jj < 4; ++jj) {
                int c = col0 + jj * 16 + llo - 2048;
                v4bf pk;
                #pragma unroll
                for (int r = 0; r < 4; ++r) pk[r] = (__bf16)acc[i][jj][r];
                *(v4bf*)&vt_out[((size_t)(bidx * NH + (c >> 6)) * HS + (c & 63)) * TT + t0] = pk;
            }
        }
    }
}

// -------- out-proj GEMM: 64x128 tiles, dbuf -> 512 blocks (r12-validated) --------
__global__ __launch_bounds__(256) void gemm_bt64_kernel(
    const __bf16* __restrict__ A, const __bf16* __restrict__ Bt, int K,
    float* __restrict__ f_out, const float* __restrict__ bias)
{
    __shared__ __align__(16) __bf16 As[2][64 * 64];
    __shared__ __align__(16) __bf16 Bs[2][128 * 64];
    const int tid = threadIdx.x;
    const int w = tid >> 6, l = tid & 63;
    const int wm = w & 1, wn = w >> 1;
    const int lhi = l >> 4, llo = l & 15;
    const int sw0 = ((lhi ^ (llo & 7)) << 3);
    const int sw1 = sw0 ^ 32;

    const int lin = blockIdx.x;
    const int xcd = lin & 7, j = lin >> 3;
    const int bm = xcd * 8 + (j & 7);
    const int bn = j >> 3;

    v4f acc[2][4];
    #pragma unroll
    for (int i = 0; i < 2; ++i)
        #pragma unroll
        for (int jj = 0; jj < 4; ++jj)
            #pragma unroll
            for (int r = 0; r < 4; ++r) acc[i][jj][r] = 0.f;

    const __bf16* Ab = A  + (size_t)bm * 64 * K;
    const __bf16* Bb = Bt + (size_t)bn * 128 * K;

    const int niter = K >> 6;
    {
        #pragma unroll
        for (int i = 0; i < 2; ++i) {
            int p = i * 256 + tid, row = p >> 3, lc = (p & 7) ^ (row & 7);
            gl_lds16(Ab + (size_t)row * K + lc * 8, As[0] + p * 8);
        }
        #pragma unroll
        for (int i = 0; i < 4; ++i) {
            int p = i * 256 + tid, row = p >> 3, lc = (p & 7) ^ (row & 7);
            gl_lds16(Bb + (size_t)row * K + lc * 8, Bs[0] + p * 8);
        }
    }

    for (int it = 0; it < niter; ++it) {
        const int buf = it & 1;
        __syncthreads();
        if (it + 1 < niter) {
            const int k0 = (it + 1) * 64;
            #pragma unroll
            for (int i = 0; i < 2; ++i) {
                int p = i * 256 + tid, row = p >> 3, lc = (p & 7) ^ (row & 7);
                gl_lds16(Ab + (size_t)row * K + k0 + lc * 8, As[buf ^ 1] + p * 8);
            }
            #pragma unroll
            for (int i = 0; i < 4; ++i) {
                int p = i * 256 + tid, row = p >> 3, lc = (p & 7) ^ (row & 7);
                gl_lds16(Bb + (size_t)row * K + k0 + lc * 8, Bs[buf ^ 1] + p * 8);
            }
        }
        #pragma unroll
        for (int kk = 0; kk < 64; kk += 32) {
            const int sw = kk ? sw1 : sw0;
            v8bf a[2], b[4];
            #pragma unroll
            for (int i = 0; i < 2; ++i)
                a[i] = *(const v8bf*)&As[buf][(wm * 32 + i * 16 + llo) * 64 + sw];
            #pragma unroll
            for (int jj = 0; jj < 4; ++jj)
                b[jj] = *(const v8bf*)&Bs[buf][(wn * 64 + jj * 16 + llo) * 64 + sw];
            #pragma unroll
            for (int i = 0; i < 2; ++i)
                #pragma unroll
                for (int jj = 0; jj < 4; ++jj)
                    acc[i][jj] = __builtin_amdgcn_mfma_f32_16x16x32_bf16(a[i], b[jj], acc[i][jj], 0, 0, 0);
        }
    }

    const int row0 = bm * 64 + wm * 32;
    const int col0 = bn * 128 + wn * 64;
    #pragma unroll
    for (int jj = 0; jj < 4; ++jj) {
        int c = col0 + jj * 16 + llo;
        float bv = bias[c];
        #pragma unroll
        for (int i = 0; i < 2; ++i) {
            int rbase = row0 + i * 16 + lhi * 4;
            #pragma unroll
            for (int r = 0; r < 4; ++r)
                f_out[(size_t)(rbase + r) * DE + c] = acc[i][jj][r] + bv;
        }
    }
}

// ---------------- flash attention v7: dbuf staging + XOR swizzle, 40KB LDS (4 blocks/CU),
// balanced perm'd supertile map ----------------
__device__ __forceinline__ v4f bf_mfma(v8bf a, v8bf b, v4f c) {
    return __builtin_amdgcn_mfma_f32_16x16x32_bf16(a, b, c, 0, 0, 0);
}

__device__ __forceinline__ void stage_kv(
    const __bf16* __restrict__ kb, const __bf16* __restrict__ vb,
    __bf16* Ksb, __bf16* Vsb, int k0, int tid)
{
    #pragma unroll
    for (int i = 0; i < 2; ++i) {
        int p   = i * 256 + tid;
        int row = p >> 3;
        int lc  = (p & 7) ^ (row & 7);
        gl_lds16(kb + (size_t)(k0 + row) * 2048 + lc * 8, Ksb + p * 8);
        gl_lds16(vb + (size_t)row * TT + k0 + lc * 8,     Vsb + p * 8);
    }
}

template<bool DIAG>
__device__ __forceinline__ void attn_compute(
    const __bf16* __restrict__ Ksb, const __bf16* __restrict__ Vsb,
    __bf16* __restrict__ PsW, int k0, int r0, int lhi, int llo, int sw0, int sw1,
    v8bf aq0, v8bf aq1, v4f (&o)[4], float (&l_part)[4])
{
    v4f sacc[4];
    #pragma unroll
    for (int n = 0; n < 4; ++n)
        #pragma unroll
        for (int r = 0; r < 4; ++r) sacc[n][r] = 0.f;
    #pragma unroll
    for (int n = 0; n < 4; ++n) {
        v8bf bk0 = *(const v8bf*)&Ksb[(n * 16 + llo) * 64 + sw0];
        v8bf bk1 = *(const v8bf*)&Ksb[(n * 16 + llo) * 64 + sw1];
        sacc[n] = bf_mfma(aq0, bk0, sacc[n]);
        sacc[n] = bf_mfma(aq1, bk1, sacc[n]);
    }

    float prob[4][4];
    #pragma unroll
    for (int n = 0; n < 4; ++n) {
        int colg = k0 + n * 16 + llo;
        #pragma unroll
        for (int r = 0; r < 4; ++r) {
            float s2 = sacc[n][r] * 0.18033688f;   // 0.125 * log2(e)
            if (DIAG) { int rowg = r0 + lhi * 4 + r; if (colg > rowg) s2 = -1e30f; }
            float p = exp2f(s2);
            prob[n][r] = p;
            l_part[r] += p;
        }
    }

    // P store: [16][64] with granule swizzle g' = g ^ (row&7)
    #pragma unroll
    for (int r = 0; r < 4; ++r) {
        int prow = lhi * 4 + r;
        #pragma unroll
        for (int n = 0; n < 4; ++n) {
            int g = (n * 2 + (llo >> 3)) ^ (prow & 7);
            PsW[prow * 64 + g * 8 + (llo & 7)] = (__bf16)prob[n][r];
        }
    }

    #pragma unroll
    for (int kk = 0; kk < 64; kk += 32) {
        v8bf ap = *(const v8bf*)&PsW[llo * 64 + (((kk >> 3) + lhi) ^ (llo & 7)) * 8];
        const int sw = kk ? sw1 : sw0;
        #pragma unroll
        for (int n = 0; n < 4; ++n) {
            v8bf bv = *(const v8bf*)&Vsb[(n * 16 + llo) * 64 + sw];
            o[n] = bf_mfma(ap, bv, o[n]);
        }
    }
}

__global__ __launch_bounds__(256) void attn_kernel(
    const __bf16* __restrict__ qk, const __bf16* __restrict__ vt,
    __bf16* __restrict__ att)
{
    __shared__ __align__(16) __bf16 Ks[2][64 * 64];
    __shared__ __align__(16) __bf16 Vs[2][64 * 64];
    __shared__ __align__(16) __bf16 Ps[4][16 * 64];   // 8KB; block total 40KB = 4 blocks/CU

    const int tid = threadIdx.x;
    const int w = tid >> 6, l = tid & 63;
    const int lhi = l >> 4, llo = l & 15;
    const int sw0 = ((lhi ^ (llo & 7)) << 3);
    const int sw1 = sw0 ^ 32;
    const int bh = blockIdx.x & 63;          // same-bh blocks 64 apart -> same XCD
    const int k = blockIdx.x >> 6;
    const int qt = (k & 4) ? (k >= 12 ? k - 12 : k + 4) : (15 - k);
    const int b = bh >> 4, h = bh & 15;

    const __bf16* qbase = qk + (size_t)b * TT * 2048 + h * HS;
    const __bf16* kbase = qk + (size_t)b * TT * 2048 + 1024 + h * HS;
    const __bf16* vbase = vt + (size_t)bh * HS * TT;
    __bf16* PsW = &Ps[w][0];

    const int r0 = qt * 64 + w * 16;

    stage_kv(kbase, vbase, Ks[0], Vs[0], 0, tid);

    v8bf aq0 = *(const v8bf*)&qbase[(size_t)(r0 + llo) * 2048 + lhi * 8];
    v8bf aq1 = *(const v8bf*)&qbase[(size_t)(r0 + llo) * 2048 + 32 + lhi * 8];

    float l_part[4] = {0.f, 0.f, 0.f, 0.f};
    v4f o[4];
    #pragma unroll
    for (int n = 0; n < 4; ++n)
        #pragma unroll
        for (int r = 0; r < 4; ++r) o[n][r] = 0.f;

    for (int kt = 0; kt < qt; ++kt) {
        const int buf = kt & 1;
        __syncthreads();
        stage_kv(kbase, vbase, Ks[buf ^ 1], Vs[buf ^ 1], (kt + 1) * 64, tid);
        attn_compute<false>(Ks[buf], Vs[buf], PsW, kt * 64, r0, lhi, llo, sw0, sw1, aq0, aq1, o, l_part);
    }
    __syncthreads();
    attn_compute<true>(Ks[qt & 1], Vs[qt & 1], PsW, qt * 64, r0, lhi, llo, sw0, sw1, aq0, aq1, o, l_part);

    #pragma unroll
    for (int r = 0; r < 4; ++r) {
        float s = l_part[r];
        #pragma unroll
        for (int msk = 1; msk < 16; msk <<= 1) s += __shfl_xor(s, msk, 64);
        float inv = 1.f / s;
        int rowg = b * TT + r0 + lhi * 4 + r;
        #pragma unroll
        for (int n = 0; n < 4; ++n)
            att[(size_t)rowg * DE + h * HS + n * 16 + llo] = (__bf16)(o[n][r] * inv);
    }
}

extern "C" void kernel_launch(void* const* d_in, const int* in_sizes, int n_in,
                              void* d_out, int out_size, void* d_ws, size_t ws_size,
                              hipStream_t stream)
{
    const float* x  = (const float*)d_in[0];
    const float* Wq = (const float*)d_in[1];
    const float* Wk = (const float*)d_in[2];
    const float* Wv = (const float*)d_in[3];
    const float* Wo = (const float*)d_in[4];
    const float* bo = (const float*)d_in[5];
    float* out = (float*)d_out;

    char* ws = (char*)d_ws;
    __bf16* xb  = (__bf16*)(ws);                 // 8 MB   [4096][1024]
    __bf16* Wt  = (__bf16*)(ws + 8388608);       // 6 MB   [3072][1024]
    __bf16* Wob = (__bf16*)(ws + 14680064);      // 2 MB   [1024][1024]
    __bf16* qk  = (__bf16*)(ws + 16777216);      // 16 MB  [4096][2048]
    __bf16* vt  = (__bf16*)(ws + 33554432);      // 8 MB   [64][64][1024]
    __bf16* att = (__bf16*)(ws + 41943040);      // 8 MB   [4096][1024]

    // fused prep: casts (5120 blocks) + weight transpose (768 blocks)
    prep_all_kernel<<<5888, 256, 0, stream>>>(x, xb, Wo, Wob, Wq, Wk, Wv, Wt);
    // QKV: M=4096, N=3072, K=1024 -> 768 blocks, single-buffered, 3 blocks/CU co-resident
    gemm_bt_kernel<<<768, 256, 0, stream>>>(xb, Wt, 1024, qk, vt);
    // attention: 1024 blocks = 64 bh x 16 q-supertiles, 4 blocks/CU, balanced perm map
    attn_kernel<<<1024, 256, 0, stream>>>(qk, vt, att);
    // out proj: M=4096, N=1024, K=1024 -> 512 blocks (8 xcd x 8 bm x 8 bn), 64x128 tiles
    gemm_bt64_kernel<<<512, 256, 0, stream>>>(att, Wob, 1024, out, bo);
}